// Round 1
// 298.048 us; speedup vs baseline: 1.0499x; 1.0499x over previous
//
#include <hip/hip_runtime.h>
#include <hip/hip_bf16.h>
#include <hip/hip_fp16.h>

#define FDIM 64

// Bucketed CSR build parameters
#define NBLK_G 256        // chunk-grid for p1
#define CHUNK_CAP 8192    // max edges per chunk block (32 KB LDS stage)
#define BKT_SHIFT 7
#define BKT_NODES 128     // dest nodes per bucket
#define NB_MAX 512        // max buckets (N <= 65536)
#define STCAP 8192        // P4 LDS stage cap (edges)

__device__ __forceinline__ int clampi(int v, int n) { return min(max(v, 0), n - 1); }

// ---- P1: block-local bin + contiguous stage + counts + starts table --------
__global__ __launch_bounds__(512) void p1_bin_stage(
    const int* __restrict__ rows, const int* __restrict__ cols,
    unsigned* __restrict__ pairs1, int* __restrict__ blockcnt,
    int* __restrict__ startsTbl, int n, int E, int nb, int chunk)
{
    __shared__ unsigned stage[CHUNK_CAP];
    __shared__ int hist[NB_MAX];
    __shared__ int curs[NB_MAX];
    int tid = threadIdx.x;
    int base = blockIdx.x * chunk;
    int cnt = E - base; if (cnt > chunk) cnt = chunk; if (cnt < 0) cnt = 0;
    for (int i = tid; i < NB_MAX; i += 512) hist[i] = 0;
    __syncthreads();
    for (int i = tid; i < cnt; i += 512)
        atomicAdd(&hist[clampi(cols[base + i], n) >> BKT_SHIFT], 1);
    __syncthreads();
    for (int b = tid; b < nb; b += 512) blockcnt[blockIdx.x * nb + b] = hist[b];
    __syncthreads();
    for (int off = 1; off < NB_MAX; off <<= 1) {
        int t = (tid >= off) ? hist[tid - off] : 0;
        __syncthreads();
        hist[tid] += t;
        __syncthreads();
    }
    curs[tid] = (tid == 0) ? 0 : hist[tid - 1];
    __syncthreads();
    // persist chunk-local exclusive starts BEFORE atomics mutate curs
    for (int b = tid; b < nb; b += 512) startsTbl[blockIdx.x * nb + b] = curs[b];
    __syncthreads();
    for (int i = tid; i < cnt; i += 512) {
        int c = clampi(cols[base + i], n);
        int r = clampi(rows[base + i], n);
        int p = atomicAdd(&curs[c >> BKT_SHIFT], 1);
        stage[p] = ((unsigned)r << 16) | (unsigned)c;
    }
    __syncthreads();
    for (int i = tid; i < cnt; i += 512) pairs1[base + i] = stage[i];
}

// --------------------- P2a: per-bucket column scan (1 wave / bucket) --------
__global__ __launch_bounds__(64) void p2a_colscan(
    int* __restrict__ blockcnt, int* __restrict__ bucketTot, int nb, int nblk)
{
    int b = blockIdx.x;
    int lane = threadIdx.x;
    int chunk = (nblk + 63) >> 6;
    int beg = lane * chunk;
    int endi = min(beg + chunk, nblk);
    int vals[8];
    int s = 0;
    for (int i = beg, j = 0; i < endi; ++i, ++j) {
        vals[j] = blockcnt[(size_t)i * nb + b];
        s += vals[j];
    }
    int incl = s;
#pragma unroll
    for (int o = 1; o < 64; o <<= 1) {
        int t = __shfl_up(incl, o, 64);
        if (lane >= o) incl += t;
    }
    int run = incl - s;
    for (int i = beg, j = 0; i < endi; ++i, ++j) {
        int t = vals[j];
        blockcnt[(size_t)i * nb + b] = run;
        run += t;
    }
    if (lane == 63) bucketTot[b] = incl;
}

// --------------------- P2b: bucket totals -> bucket bases -------------------
__global__ __launch_bounds__(512) void p2b_basescan(
    const int* __restrict__ bucketTot, int* __restrict__ bucketBase, int nb)
{
    __shared__ int tot[NB_MAX];
    int tid = threadIdx.x;
    tot[tid] = (tid < nb) ? bucketTot[tid] : 0;
    __syncthreads();
    for (int off = 1; off < NB_MAX; off <<= 1) {
        int t = (tid >= off) ? tot[tid - off] : 0;
        __syncthreads();
        tot[tid] += t;
        __syncthreads();
    }
    if (tid < nb) bucketBase[tid] = (tid == 0) ? 0 : tot[tid - 1];
    if (tid == 0) bucketBase[nb] = tot[nb - 1];
}

// ---- P4: per-bucket fine CSR, staging runs straight from pairs1 ------------
__global__ __launch_bounds__(256) void p4_fine2(
    const unsigned* __restrict__ pairs1, const int* __restrict__ blockcnt,
    const int* __restrict__ startsTbl, const int* __restrict__ bucketBase,
    int* __restrict__ rowptr, unsigned short* __restrict__ csridx,
    int n, int E, int nb, int chunk, int nblk)
{
    __shared__ unsigned st[STCAP];
    __shared__ int h[BKT_NODES];
    __shared__ int cur[BKT_NODES];
    int tid = threadIdx.x;
    int b = blockIdx.x;
    int beg = bucketBase[b], end = bucketBase[b + 1];
    int cnt = end - beg;
    for (int i = tid; i < BKT_NODES; i += 256) h[i] = 0;
    __syncthreads();
    bool fit = (cnt <= STCAP);     // block-uniform -> in-branch barriers legal
    if (fit) {
        for (int i = tid; i < nblk; i += 256) {
            int ccnt = E - i * chunk; if (ccnt > chunk) ccnt = chunk; if (ccnt < 0) ccnt = 0;
            int stt = startsTbl[(size_t)i * nb + b];
            int enn = (b + 1 < nb) ? startsTbl[(size_t)i * nb + b + 1] : ccnt;
            int dst = blockcnt[(size_t)i * nb + b];
            for (int j = stt; j < enn; ++j)
                st[dst + (j - stt)] = pairs1[(size_t)i * chunk + j];
        }
        __syncthreads();
        for (int i = tid; i < cnt; i += 256)
            atomicAdd(&h[st[i] & (BKT_NODES - 1)], 1);
    } else {
        for (int i = tid; i < nblk; i += 256) {
            int ccnt = E - i * chunk; if (ccnt > chunk) ccnt = chunk; if (ccnt < 0) ccnt = 0;
            int stt = startsTbl[(size_t)i * nb + b];
            int enn = (b + 1 < nb) ? startsTbl[(size_t)i * nb + b + 1] : ccnt;
            for (int j = stt; j < enn; ++j)
                atomicAdd(&h[pairs1[(size_t)i * chunk + j] & (BKT_NODES - 1)], 1);
        }
    }
    // barrier between histogram atomics and scan (round-9 race fix)
    __syncthreads();
    for (int off = 1; off < BKT_NODES; off <<= 1) {
        int t = (tid >= off && tid < BKT_NODES) ? h[tid - off] : 0;
        __syncthreads();
        if (tid < BKT_NODES) h[tid] += t;
        __syncthreads();
    }
    if (tid < BKT_NODES) {
        int node = b * BKT_NODES + tid;
        int startl = (tid == 0) ? 0 : h[tid - 1];
        cur[tid] = startl;
        if (node < n) rowptr[node] = beg + startl;
    }
    __syncthreads();
    if (fit) {
        for (int i = tid; i < cnt; i += 256) {
            unsigned pk = st[i];
            int p = atomicAdd(&cur[pk & (BKT_NODES - 1)], 1);
            csridx[beg + p] = (unsigned short)(pk >> 16);
        }
    } else {
        for (int i = tid; i < nblk; i += 256) {
            int ccnt = E - i * chunk; if (ccnt > chunk) ccnt = chunk; if (ccnt < 0) ccnt = 0;
            int stt = startsTbl[(size_t)i * nb + b];
            int enn = (b + 1 < nb) ? startsTbl[(size_t)i * nb + b + 1] : ccnt;
            for (int j = stt; j < enn; ++j) {
                unsigned pk = pairs1[(size_t)i * chunk + j];
                int p = atomicAdd(&cur[pk & (BKT_NODES - 1)], 1);
                csridx[beg + p] = (unsigned short)(pk >> 16);
            }
        }
    }
    if (b == nb - 1 && tid == 0) rowptr[n] = E;
}

// ------ GEMM precompute: P = src@W (fp16), Q = src@R + b (fp32) -------------
// mean-agg is linear, so agg(x)@W == agg(x@W): hoist both matmuls out of the
// gather kernel. Weights live in REGISTERS (wcol/rcol, 128 VGPR, static
// indices via full unroll); the per-row broadcast uses v_readlane (VALU pipe)
// so this kernel issues ZERO ds_read in the hot loop — the old epilogue's
// 64 ds_read_b128/node (~62 us/dispatch of LDS-pipe serialization) is gone.
// Q32 may alias src: each wave reads its row fully into registers (xv) before
// the row's writes; rows are wave-disjoint.
__global__ __launch_bounds__(256) void gemm_pq_kernel(
    const float* __restrict__ src, const float* __restrict__ W,
    const float* __restrict__ R, const float* __restrict__ bvec,
    __half* __restrict__ P16, float* __restrict__ Q32, int n)
{
    int lane = threadIdx.x & 63;
    int wv = threadIdx.x >> 6;
    float wcol[FDIM], rcol[FDIM];
#pragma unroll
    for (int k = 0; k < FDIM; ++k) {
        wcol[k] = W[k * FDIM + lane];   // coalesced: lane j reads W[k][j]
        rcol[k] = R[k * FDIM + lane];
    }
    float bj = bvec[lane];
    for (int row = blockIdx.x * 4 + wv; row < n; row += gridDim.x * 4) {
        float xv = src[((size_t)row << 6) + lane];
        float accP = 0.0f, accQ = bj;
#pragma unroll
        for (int k = 0; k < FDIM; ++k) {
            // wave-uniform broadcast of src[row][k] -> SGPR operand to the FMAs
            float s = __uint_as_float(
                __builtin_amdgcn_readlane(__float_as_uint(xv), k));
            accP = fmaf(s, wcol[k], accP);
            accQ = fmaf(s, rcol[k], accQ);
        }
        P16[((size_t)row << 6) + lane] = __float2half(accP);
        Q32[((size_t)row << 6) + lane] = accQ;
    }
}

// ------ Slim fused gather: out = act(dinv * sum P16[src] + Q[node]) ---------
// Gather path kept VERBATIM from the verified r7/r11 config (16 lanes x
// float2-of-halves per edge row). Dense epilogue is gone: LDS shrinks
// 37376 -> 1024 B and VGPR stays <=64, so occupancy ceiling goes 16 -> 32
// waves/CU and the LDS pipe only carries shfl + the tiny aRow bounce.
// Q is read from out32 and overwritten in place (same thread, read-then-write).
template <bool RELU, bool NORM>
__global__ __launch_bounds__(256) void fused_gather_kernel(
    const int* __restrict__ rowptr, const unsigned short* __restrict__ csridx,
    const __half* __restrict__ P16, float* __restrict__ out32, int n)
{
    __shared__ __align__(16) float aRow[4][FDIM];
    int tid = threadIdx.x;
    int lane = tid & 63, w = tid >> 6;
    int g = lane >> 4;        // edge sub-group 0..3
    int q = lane & 15;        // 4-feature chunk within row

    for (int node = blockIdx.x * 4 + w; node < n; node += gridDim.x * 4) {
        int beg = rowptr[node], end = rowptr[node + 1];
        float4 s4 = make_float4(0.f, 0.f, 0.f, 0.f);
        for (int base = beg; base < end; base += 64) {
            int cnt = end - base; if (cnt > 64) cnt = 64;
            int ei = base + lane;
            int myidx = (ei < end) ? (int)csridx[ei] : 0;
            int steps = (cnt + 3) >> 2;
            for (int t = 0; t < steps; ++t) {
                int e = (t << 2) | g;
                int sidx = __shfl(myidx, e, 64);
                if (e < cnt) {
                    const float2* rp = (const float2*)(P16 + ((size_t)sidx << 6));
                    float2 vv = rp[q];                 // 4 halves = 8 B
                    __half2 ha = *reinterpret_cast<__half2*>(&vv.x);
                    __half2 hb = *reinterpret_cast<__half2*>(&vv.y);
                    float2 fa = __half22float2(ha);
                    float2 fb = __half22float2(hb);
                    s4.x += fa.x; s4.y += fa.y; s4.z += fb.x; s4.w += fb.y;
                }
            }
        }
#pragma unroll
        for (int o = 16; o < 64; o <<= 1) {
            s4.x += __shfl_xor(s4.x, o, 64);
            s4.y += __shfl_xor(s4.y, o, 64);
            s4.z += __shfl_xor(s4.z, o, 64);
            s4.w += __shfl_xor(s4.w, o, 64);
        }
        float dinv = 1.0f / fmaxf((float)(end - beg), 1.0f);
        if (g == 0) {
            aRow[w][q * 4 + 0] = s4.x * dinv;
            aRow[w][q * 4 + 1] = s4.y * dinv;
            aRow[w][q * 4 + 2] = s4.z * dinv;
            aRow[w][q * 4 + 3] = s4.w * dinv;
        }
        // wave-local LDS RAW: ordered within the wave, no barrier needed
        float acc = aRow[w][lane] + out32[((size_t)node << 6) + lane];
        if (RELU) acc = fmaxf(acc, 0.0f);
        if (NORM) {
            float ss = acc * acc;
#pragma unroll
            for (int o = 32; o; o >>= 1) ss += __shfl_xor(ss, o, 64);
            acc *= 1.0f / fmaxf(sqrtf(ss), 1e-12f);
        }
        out32[((size_t)node << 6) + lane] = acc;
    }
}

// ----------------- Atomic scatter path (fallback, 13.0 MB ws) ---------------
__global__ __launch_bounds__(256) void scatter_kernel(
    const float* __restrict__ src, const int* __restrict__ rows, const int* __restrict__ cols,
    float* __restrict__ agg, float* __restrict__ deg, int n, long long total)
{
    long long gid = (long long)blockIdx.x * 256 + threadIdx.x;
    if (gid >= total) return;
    int e = (int)(gid >> 6);
    int f = (int)(gid & 63);
    int r = clampi(rows[e], n), c = clampi(cols[e], n);
    atomicAdd(&agg[(long long)c * FDIM + f], src[(long long)r * FDIM + f]);
    if (f == 0) atomicAdd(&deg[c], 1.0f);
}

template <bool RELU, bool NORM>
__global__ __launch_bounds__(256) void dense_kernel(
    const float* __restrict__ agg, const float* __restrict__ deg, const float* __restrict__ x,
    const float* __restrict__ W, const float* __restrict__ b,
    const float* __restrict__ R, float* __restrict__ out, int n)
{
    __shared__ float Ws[FDIM][FDIM];
    __shared__ float Rs[FDIM][FDIM];
    __shared__ float bs[FDIM];
    __shared__ float aRow[4][FDIM];
    __shared__ float xRow[4][FDIM];
    int tid = threadIdx.x;
    for (int i = tid; i < FDIM * FDIM; i += 256) {
        Ws[i >> 6][i & 63] = W[i];
        Rs[i >> 6][i & 63] = R[i];
    }
    if (tid < FDIM) bs[tid] = b[tid];
    int j = tid & 63, r = tid >> 6;
    int row = blockIdx.x * 4 + r;
    if (row < n) {
        float d = fmaxf(deg[row], 1.0f);
        aRow[r][j] = agg[(long long)row * FDIM + j] / d;
        xRow[r][j] = x[(long long)row * FDIM + j];
    }
    __syncthreads();
    if (row >= n) return;
    float acc = bs[j];
#pragma unroll
    for (int k = 0; k < FDIM; ++k)
        acc = fmaf(aRow[r][k], Ws[k][j], fmaf(xRow[r][k], Rs[k][j], acc));
    if (RELU) acc = fmaxf(acc, 0.0f);
    if (NORM) {
        float ss = acc * acc;
#pragma unroll
        for (int o = 32; o; o >>= 1) ss += __shfl_xor(ss, o, 64);
        acc *= 1.0f / fmaxf(sqrtf(ss), 1e-12f);
    }
    out[(long long)row * FDIM + j] = acc;
}

// ---------------------------------------------------------------------------
extern "C" void kernel_launch(void* const* d_in, const int* in_sizes, int n_in,
                              void* d_out, int out_size, void* d_ws, size_t ws_size,
                              hipStream_t stream)
{
    const float* x  = (const float*)d_in[0];
    const int*   e0 = (const int*)d_in[1];
    const int*   e1 = (const int*)d_in[2];
    const float* W1 = (const float*)d_in[3];
    const float* b1 = (const float*)d_in[4];
    const float* R1 = (const float*)d_in[5];
    const float* W2 = (const float*)d_in[6];
    const float* b2 = (const float*)d_in[7];
    const float* R2 = (const float*)d_in[8];
    float* out = (float*)d_out;

    const int N = in_sizes[0] / FDIM;     // 50000
    const int E = in_sizes[1] / 2;        // 1600000

    const int nb = (N + BKT_NODES - 1) >> BKT_SHIFT;
    const int chunk = (E + NBLK_G - 1) / NBLK_G;
    const int GATHER_BLOCKS = 2048;       // 8 blocks/CU at 1 KB LDS, VGPR<=64
    const int GEMM_BLOCKS = 1024;         // ~12 rows/wave, amortizes reg-W load

    // Workspace (16-B aligned): pairs1[E] u32 | csridx[E] u16 |
    // blockcnt[NBLK_G*nb] | startsTbl[NBLK_G*nb] | bucketBase[nb+1] |
    // bucketTot[nb] | rowptr[N+1] | P16[N*64] half   (~17.5 MB)
    auto align16 = [](size_t v) { return (v + 15) & ~(size_t)15; };
    size_t off = 0;
    size_t o_pairs1 = off; off = align16(off + (size_t)E * 4);
    size_t o_csr16  = off; off = align16(off + (size_t)E * 2);
    size_t o_bcnt   = off; off = align16(off + (size_t)NBLK_G * nb * 4);
    size_t o_stbl   = off; off = align16(off + (size_t)NBLK_G * nb * 4);
    size_t o_bbase  = off; off = align16(off + (size_t)(nb + 1) * 4);
    size_t o_btot   = off; off = align16(off + (size_t)nb * 4);
    size_t o_rowp   = off; off = align16(off + (size_t)(N + 1) * 4);
    size_t o_p16    = off; off = align16(off + (size_t)N * FDIM * 2);
    const size_t need1 = off;

    const bool ok1 = (ws_size >= need1) && (N <= 65536) &&
                     (chunk <= CHUNK_CAP) && (nb <= NB_MAX);

    if (ok1) {
        char* wsb = (char*)d_ws;
        unsigned*        pairs1     = (unsigned*)(wsb + o_pairs1);
        unsigned short*  csridx     = (unsigned short*)(wsb + o_csr16);
        int*             blockcnt   = (int*)(wsb + o_bcnt);
        int*             startsTbl  = (int*)(wsb + o_stbl);
        int*             bucketBase = (int*)(wsb + o_bbase);
        int*             bucketTot  = (int*)(wsb + o_btot);
        int*             rowptr     = (int*)(wsb + o_rowp);
        __half*          P16        = (__half*)(wsb + o_p16);

        // ---- Layer 1: P1 = x@W1 (fp16), Q1 = x@R1 + b1 -> d_out ----
        gemm_pq_kernel<<<GEMM_BLOCKS, 256, 0, stream>>>(
            x, W1, R1, b1, P16, out, N);
        p1_bin_stage<<<NBLK_G, 512, 0, stream>>>(e0, e0 + E, pairs1, blockcnt,
                                                 startsTbl, N, E, nb, chunk);
        p2a_colscan<<<nb, 64, 0, stream>>>(blockcnt, bucketTot, nb, NBLK_G);
        p2b_basescan<<<1, 512, 0, stream>>>(bucketTot, bucketBase, nb);
        p4_fine2<<<nb, 256, 0, stream>>>(pairs1, blockcnt, startsTbl, bucketBase,
                                         rowptr, csridx, N, E, nb, chunk, NBLK_G);
        // h = relu(mean-gather(P1) + Q1), in place over d_out
        fused_gather_kernel<true, false><<<GATHER_BLOCKS, 256, 0, stream>>>(
            rowptr, csridx, P16, out, N);

        // ---- Layer 2: P2 = h@W2 (fp16), Q2 = h@R2 + b2 (in-place over h) ----
        gemm_pq_kernel<<<GEMM_BLOCKS, 256, 0, stream>>>(
            out, W2, R2, b2, P16, out, N);
        p1_bin_stage<<<NBLK_G, 512, 0, stream>>>(e1, e1 + E, pairs1, blockcnt,
                                                 startsTbl, N, E, nb, chunk);
        p2a_colscan<<<nb, 64, 0, stream>>>(blockcnt, bucketTot, nb, NBLK_G);
        p2b_basescan<<<1, 512, 0, stream>>>(bucketTot, bucketBase, nb);
        p4_fine2<<<nb, 256, 0, stream>>>(pairs1, blockcnt, startsTbl, bucketBase,
                                         rowptr, csridx, N, E, nb, chunk, NBLK_G);
        // out = normalize(mean-gather(P2) + Q2), in place over d_out
        fused_gather_kernel<false, true><<<GATHER_BLOCKS, 256, 0, stream>>>(
            rowptr, csridx, P16, out, N);
    } else {
        // Fallback: atomic scatter path (round-3, verified)
        float* agg = (float*)d_ws;
        float* deg = agg + (long long)N * FDIM;
        float* h = out;
        const long long total = (long long)E * FDIM;
        const int sblocks = (int)((total + 255) / 256);
        const int dblocks = (N + 3) / 4;

        hipMemsetAsync(agg, 0, ((size_t)N * FDIM + N) * sizeof(float), stream);
        scatter_kernel<<<sblocks, 256, 0, stream>>>(x, e0, e0 + E, agg, deg, N, total);
        dense_kernel<true, false><<<dblocks, 256, 0, stream>>>(agg, deg, x, W1, b1, R1, h, N);

        hipMemsetAsync(agg, 0, ((size_t)N * FDIM + N) * sizeof(float), stream);
        scatter_kernel<<<sblocks, 256, 0, stream>>>(h, e1, e1 + E, agg, deg, N, total);
        dense_kernel<false, true><<<dblocks, 256, 0, stream>>>(agg, deg, h, W2, b2, R2, out, N);
    }
}

// Round 2
// 284.774 us; speedup vs baseline: 1.0988x; 1.0466x over previous
//
#include <hip/hip_runtime.h>
#include <hip/hip_bf16.h>
#include <hip/hip_fp16.h>

#define FDIM 64

// Bucketed CSR build parameters
#define NBLK_G 256        // chunk-grid for p1 (MUST equal p4 blockDim)
#define CHUNK_CAP 8192    // max edges per chunk block (32 KB LDS stage)
#define BKT_SHIFT 7
#define BKT_NODES 128     // dest nodes per bucket
#define NB_MAX 512        // max buckets (N <= 65536)
#define STCAP 8192        // P4 LDS stage cap (edges)

__device__ __forceinline__ int clampi(int v, int n) { return min(max(v, 0), n - 1); }

// ---- P1: block-local bin + contiguous stage + counts + starts table --------
// Also accumulates global bucketTot via atomics (folds old p2a's row-sum);
// bucketTot must be zeroed (hipMemsetAsync) before launch.
__global__ __launch_bounds__(512) void p1_bin_stage(
    const int* __restrict__ rows, const int* __restrict__ cols,
    unsigned* __restrict__ pairs1, int* __restrict__ blockcnt,
    int* __restrict__ startsTbl, int* __restrict__ bucketTot,
    int n, int E, int nb, int chunk)
{
    __shared__ unsigned stage[CHUNK_CAP];
    __shared__ int hist[NB_MAX];
    __shared__ int curs[NB_MAX];
    int tid = threadIdx.x;
    int base = blockIdx.x * chunk;
    int cnt = E - base; if (cnt > chunk) cnt = chunk; if (cnt < 0) cnt = 0;
    for (int i = tid; i < NB_MAX; i += 512) hist[i] = 0;
    __syncthreads();
    for (int i = tid; i < cnt; i += 512)
        atomicAdd(&hist[clampi(cols[base + i], n) >> BKT_SHIFT], 1);
    __syncthreads();
    for (int b = tid; b < nb; b += 512) {
        int hv = hist[b];
        blockcnt[blockIdx.x * nb + b] = hv;
        if (hv) atomicAdd(&bucketTot[b], hv);   // global bucket totals
    }
    __syncthreads();
    for (int off = 1; off < NB_MAX; off <<= 1) {
        int t = (tid >= off) ? hist[tid - off] : 0;
        __syncthreads();
        hist[tid] += t;
        __syncthreads();
    }
    curs[tid] = (tid == 0) ? 0 : hist[tid - 1];
    __syncthreads();
    // persist chunk-local exclusive starts BEFORE atomics mutate curs
    for (int b = tid; b < nb; b += 512) startsTbl[blockIdx.x * nb + b] = curs[b];
    __syncthreads();
    for (int i = tid; i < cnt; i += 512) {
        int c = clampi(cols[base + i], n);
        int r = clampi(rows[base + i], n);
        int p = atomicAdd(&curs[c >> BKT_SHIFT], 1);
        stage[p] = ((unsigned)r << 16) | (unsigned)c;
    }
    __syncthreads();
    for (int i = tid; i < cnt; i += 512) pairs1[base + i] = stage[i];
}

// ---- P4: per-bucket fine CSR; now self-contained (folds old p2a+p2b) -------
// Computes bucket base via in-block scan of bucketTot, and per-chunk dst
// offsets via in-block scan of its blockcnt column (thread == chunk,
// requires nblk == NBLK_G == blockDim == 256).
__global__ __launch_bounds__(256) void p4_fine2(
    const unsigned* __restrict__ pairs1, const int* __restrict__ blockcnt,
    const int* __restrict__ startsTbl, const int* __restrict__ bucketTot,
    int* __restrict__ rowptr, unsigned short* __restrict__ csridx,
    int n, int E, int nb, int chunk, int nblk)
{
    __shared__ unsigned st[STCAP];
    __shared__ int h[BKT_NODES];
    __shared__ int cur[BKT_NODES];
    __shared__ int bscan[NB_MAX];    // inclusive scan of bucketTot
    __shared__ int colv[NBLK_G];     // inclusive scan of this bucket's column
    int tid = threadIdx.x;
    int b = blockIdx.x;

    // load: bucket totals (2/thread) + this bucket's per-chunk counts
    bscan[tid]       = (tid < nb) ? bucketTot[tid] : 0;
    bscan[tid + 256] = (tid + 256 < nb) ? bucketTot[tid + 256] : 0;
    int myc = (tid < nblk) ? blockcnt[(size_t)tid * nb + b] : 0;
    colv[tid] = myc;
    if (tid < BKT_NODES) h[tid] = 0;
    __syncthreads();
    // fused Hillis-Steele: 512-wide on bscan, 256-wide on colv
    for (int off = 1; off < NB_MAX; off <<= 1) {
        int t0 = (tid >= off) ? bscan[tid - off] : 0;
        int t1 = (tid + 256 >= off) ? bscan[tid + 256 - off] : 0;
        int t2 = (off < NBLK_G && tid >= off) ? colv[tid - off] : 0;
        __syncthreads();
        bscan[tid] += t0;
        bscan[tid + 256] += t1;
        if (off < NBLK_G) colv[tid] += t2;
        __syncthreads();
    }
    int beg = (b == 0) ? 0 : bscan[b - 1];
    int cnt = bscan[b] - beg;
    int dst = colv[tid] - myc;       // exclusive: stage offset for chunk 'tid'

    bool fit = (cnt <= STCAP);       // block-uniform -> in-branch barriers legal
    if (fit) {
        if (tid < nblk) {
            int ccnt = E - tid * chunk; if (ccnt > chunk) ccnt = chunk; if (ccnt < 0) ccnt = 0;
            int stt = startsTbl[(size_t)tid * nb + b];
            int enn = (b + 1 < nb) ? startsTbl[(size_t)tid * nb + b + 1] : ccnt;
            const unsigned* srcp = pairs1 + (size_t)tid * chunk;
            for (int j = stt; j < enn; ++j)
                st[dst + (j - stt)] = srcp[j];
        }
        __syncthreads();
        for (int i = tid; i < cnt; i += 256)
            atomicAdd(&h[st[i] & (BKT_NODES - 1)], 1);
    } else {
        for (int i = tid; i < nblk; i += 256) {
            int ccnt = E - i * chunk; if (ccnt > chunk) ccnt = chunk; if (ccnt < 0) ccnt = 0;
            int stt = startsTbl[(size_t)i * nb + b];
            int enn = (b + 1 < nb) ? startsTbl[(size_t)i * nb + b + 1] : ccnt;
            for (int j = stt; j < enn; ++j)
                atomicAdd(&h[pairs1[(size_t)i * chunk + j] & (BKT_NODES - 1)], 1);
        }
    }
    // barrier between histogram atomics and scan (round-9 race fix)
    __syncthreads();
    for (int off = 1; off < BKT_NODES; off <<= 1) {
        int t = (tid >= off && tid < BKT_NODES) ? h[tid - off] : 0;
        __syncthreads();
        if (tid < BKT_NODES) h[tid] += t;
        __syncthreads();
    }
    if (tid < BKT_NODES) {
        int node = b * BKT_NODES + tid;
        int startl = (tid == 0) ? 0 : h[tid - 1];
        cur[tid] = startl;
        if (node < n) rowptr[node] = beg + startl;
    }
    __syncthreads();
    if (fit) {
        for (int i = tid; i < cnt; i += 256) {
            unsigned pk = st[i];
            int p = atomicAdd(&cur[pk & (BKT_NODES - 1)], 1);
            csridx[beg + p] = (unsigned short)(pk >> 16);
        }
    } else {
        for (int i = tid; i < nblk; i += 256) {
            int ccnt = E - i * chunk; if (ccnt > chunk) ccnt = chunk; if (ccnt < 0) ccnt = 0;
            int stt = startsTbl[(size_t)i * nb + b];
            int enn = (b + 1 < nb) ? startsTbl[(size_t)i * nb + b + 1] : ccnt;
            for (int j = stt; j < enn; ++j) {
                unsigned pk = pairs1[(size_t)i * chunk + j];
                int p = atomicAdd(&cur[pk & (BKT_NODES - 1)], 1);
                csridx[beg + p] = (unsigned short)(pk >> 16);
            }
        }
    }
    if (b == nb - 1 && tid == 0) rowptr[n] = E;
}

// ------ GEMM precompute: P = src@W (fp16), Q = src@R + b (fp32) -------------
// mean-agg is linear, so agg(x)@W == agg(x@W). Weights register-resident;
// per-row broadcast via v_readlane. Q32 may alias src (wave reads its row
// before writing; rows are wave-disjoint).
__global__ __launch_bounds__(256) void gemm_pq_kernel(
    const float* __restrict__ src, const float* __restrict__ W,
    const float* __restrict__ R, const float* __restrict__ bvec,
    __half* __restrict__ P16, float* __restrict__ Q32, int n)
{
    int lane = threadIdx.x & 63;
    int wv = threadIdx.x >> 6;
    float wcol[FDIM], rcol[FDIM];
#pragma unroll
    for (int k = 0; k < FDIM; ++k) {
        wcol[k] = W[k * FDIM + lane];   // coalesced: lane j reads W[k][j]
        rcol[k] = R[k * FDIM + lane];
    }
    float bj = bvec[lane];
    for (int row = blockIdx.x * 4 + wv; row < n; row += gridDim.x * 4) {
        float xv = src[((size_t)row << 6) + lane];
        float accP = 0.0f, accQ = bj;
#pragma unroll
        for (int k = 0; k < FDIM; ++k) {
            float s = __uint_as_float(
                __builtin_amdgcn_readlane(__float_as_uint(xv), k));
            accP = fmaf(s, wcol[k], accP);
            accQ = fmaf(s, rcol[k], accQ);
        }
        P16[((size_t)row << 6) + lane] = __float2half(accP);
        Q32[((size_t)row << 6) + lane] = accQ;
    }
}

// ------ Slim fused gather: out = act(dinv * sum P16[src] + Q[node]) ---------
// r2 change: 8 lanes x float4 (16 B) per edge row instead of 16 lanes x 8 B.
// Halves VMEM instruction count (the gather was VMEM-issue-bound: E*16 loads
// = ~100K VMEM/CU = ~42 us at 1/cy issue) and doubles rows in flight (8
// edges/step). Same bytes fetched. Q read from out32 and overwritten in place
// (same thread, read-then-write).
template <bool RELU, bool NORM>
__global__ __launch_bounds__(256) void fused_gather_kernel(
    const int* __restrict__ rowptr, const unsigned short* __restrict__ csridx,
    const __half* __restrict__ P16, float* __restrict__ out32, int n)
{
    __shared__ __align__(16) float aRow[4][FDIM];
    int tid = threadIdx.x;
    int lane = tid & 63, w = tid >> 6;
    int g = lane >> 3;        // edge sub-group 0..7
    int q = lane & 7;         // 8-feature chunk within row

    for (int node = blockIdx.x * 4 + w; node < n; node += gridDim.x * 4) {
        int beg = rowptr[node], end = rowptr[node + 1];
        float s0 = 0.f, s1 = 0.f, s2 = 0.f, s3 = 0.f,
              s4 = 0.f, s5 = 0.f, s6 = 0.f, s7 = 0.f;
        for (int base = beg; base < end; base += 64) {
            int cnt = end - base; if (cnt > 64) cnt = 64;
            int ei = base + lane;
            int myidx = (ei < end) ? (int)csridx[ei] : 0;
            int steps = (cnt + 7) >> 3;
            for (int t = 0; t < steps; ++t) {
                int e = (t << 3) | g;
                int sidx = __shfl(myidx, e, 64);
                if (e < cnt) {
                    const float4* rp = (const float4*)(P16 + ((size_t)sidx << 6));
                    float4 vv = rp[q];                 // 8 halves = 16 B
                    __half2 h0 = *reinterpret_cast<__half2*>(&vv.x);
                    __half2 h1 = *reinterpret_cast<__half2*>(&vv.y);
                    __half2 h2 = *reinterpret_cast<__half2*>(&vv.z);
                    __half2 h3 = *reinterpret_cast<__half2*>(&vv.w);
                    float2 f0 = __half22float2(h0);
                    float2 f1 = __half22float2(h1);
                    float2 f2 = __half22float2(h2);
                    float2 f3 = __half22float2(h3);
                    s0 += f0.x; s1 += f0.y; s2 += f1.x; s3 += f1.y;
                    s4 += f2.x; s5 += f2.y; s6 += f3.x; s7 += f3.y;
                }
            }
        }
#pragma unroll
        for (int o = 8; o < 64; o <<= 1) {
            s0 += __shfl_xor(s0, o, 64);
            s1 += __shfl_xor(s1, o, 64);
            s2 += __shfl_xor(s2, o, 64);
            s3 += __shfl_xor(s3, o, 64);
            s4 += __shfl_xor(s4, o, 64);
            s5 += __shfl_xor(s5, o, 64);
            s6 += __shfl_xor(s6, o, 64);
            s7 += __shfl_xor(s7, o, 64);
        }
        float dinv = 1.0f / fmaxf((float)(end - beg), 1.0f);
        if (g == 0) {
            float4* ar = (float4*)&aRow[w][q * 8];
            ar[0] = make_float4(s0 * dinv, s1 * dinv, s2 * dinv, s3 * dinv);
            ar[1] = make_float4(s4 * dinv, s5 * dinv, s6 * dinv, s7 * dinv);
        }
        // wave-local LDS RAW: ordered within the wave, no barrier needed
        float acc = aRow[w][lane] + out32[((size_t)node << 6) + lane];
        if (RELU) acc = fmaxf(acc, 0.0f);
        if (NORM) {
            float ss = acc * acc;
#pragma unroll
            for (int o = 32; o; o >>= 1) ss += __shfl_xor(ss, o, 64);
            acc *= 1.0f / fmaxf(sqrtf(ss), 1e-12f);
        }
        out32[((size_t)node << 6) + lane] = acc;
    }
}

// ----------------- Atomic scatter path (fallback, 13.0 MB ws) ---------------
__global__ __launch_bounds__(256) void scatter_kernel(
    const float* __restrict__ src, const int* __restrict__ rows, const int* __restrict__ cols,
    float* __restrict__ agg, float* __restrict__ deg, int n, long long total)
{
    long long gid = (long long)blockIdx.x * 256 + threadIdx.x;
    if (gid >= total) return;
    int e = (int)(gid >> 6);
    int f = (int)(gid & 63);
    int r = clampi(rows[e], n), c = clampi(cols[e], n);
    atomicAdd(&agg[(long long)c * FDIM + f], src[(long long)r * FDIM + f]);
    if (f == 0) atomicAdd(&deg[c], 1.0f);
}

template <bool RELU, bool NORM>
__global__ __launch_bounds__(256) void dense_kernel(
    const float* __restrict__ agg, const float* __restrict__ deg, const float* __restrict__ x,
    const float* __restrict__ W, const float* __restrict__ b,
    const float* __restrict__ R, float* __restrict__ out, int n)
{
    __shared__ float Ws[FDIM][FDIM];
    __shared__ float Rs[FDIM][FDIM];
    __shared__ float bs[FDIM];
    __shared__ float aRow[4][FDIM];
    __shared__ float xRow[4][FDIM];
    int tid = threadIdx.x;
    for (int i = tid; i < FDIM * FDIM; i += 256) {
        Ws[i >> 6][i & 63] = W[i];
        Rs[i >> 6][i & 63] = R[i];
    }
    if (tid < FDIM) bs[tid] = b[tid];
    int j = tid & 63, r = tid >> 6;
    int row = blockIdx.x * 4 + r;
    if (row < n) {
        float d = fmaxf(deg[row], 1.0f);
        aRow[r][j] = agg[(long long)row * FDIM + j] / d;
        xRow[r][j] = x[(long long)row * FDIM + j];
    }
    __syncthreads();
    if (row >= n) return;
    float acc = bs[j];
#pragma unroll
    for (int k = 0; k < FDIM; ++k)
        acc = fmaf(aRow[r][k], Ws[k][j], fmaf(xRow[r][k], Rs[k][j], acc));
    if (RELU) acc = fmaxf(acc, 0.0f);
    if (NORM) {
        float ss = acc * acc;
#pragma unroll
        for (int o = 32; o; o >>= 1) ss += __shfl_xor(ss, o, 64);
        acc *= 1.0f / fmaxf(sqrtf(ss), 1e-12f);
    }
    out[(long long)row * FDIM + j] = acc;
}

// ---------------------------------------------------------------------------
extern "C" void kernel_launch(void* const* d_in, const int* in_sizes, int n_in,
                              void* d_out, int out_size, void* d_ws, size_t ws_size,
                              hipStream_t stream)
{
    const float* x  = (const float*)d_in[0];
    const int*   e0 = (const int*)d_in[1];
    const int*   e1 = (const int*)d_in[2];
    const float* W1 = (const float*)d_in[3];
    const float* b1 = (const float*)d_in[4];
    const float* R1 = (const float*)d_in[5];
    const float* W2 = (const float*)d_in[6];
    const float* b2 = (const float*)d_in[7];
    const float* R2 = (const float*)d_in[8];
    float* out = (float*)d_out;

    const int N = in_sizes[0] / FDIM;     // 50000
    const int E = in_sizes[1] / 2;        // 1600000

    const int nb = (N + BKT_NODES - 1) >> BKT_SHIFT;
    const int chunk = (E + NBLK_G - 1) / NBLK_G;
    const int GATHER_BLOCKS = 2048;       // 1 KB LDS, VGPR ~64-72
    const int GEMM_BLOCKS = 1024;         // ~12 rows/wave, amortizes reg-W load

    // Workspace (16-B aligned): pairs1[E] u32 | csridx[E] u16 |
    // blockcnt[NBLK_G*nb] | startsTbl[NBLK_G*nb] | bucketTot[nb] |
    // rowptr[N+1] | P16[N*64] half   (~17.5 MB)
    auto align16 = [](size_t v) { return (v + 15) & ~(size_t)15; };
    size_t off = 0;
    size_t o_pairs1 = off; off = align16(off + (size_t)E * 4);
    size_t o_csr16  = off; off = align16(off + (size_t)E * 2);
    size_t o_bcnt   = off; off = align16(off + (size_t)NBLK_G * nb * 4);
    size_t o_stbl   = off; off = align16(off + (size_t)NBLK_G * nb * 4);
    size_t o_btot   = off; off = align16(off + (size_t)nb * 4);
    size_t o_rowp   = off; off = align16(off + (size_t)(N + 1) * 4);
    size_t o_p16    = off; off = align16(off + (size_t)N * FDIM * 2);
    const size_t need1 = off;

    const bool ok1 = (ws_size >= need1) && (N <= 65536) &&
                     (chunk <= CHUNK_CAP) && (nb <= NB_MAX);

    if (ok1) {
        char* wsb = (char*)d_ws;
        unsigned*        pairs1     = (unsigned*)(wsb + o_pairs1);
        unsigned short*  csridx     = (unsigned short*)(wsb + o_csr16);
        int*             blockcnt   = (int*)(wsb + o_bcnt);
        int*             startsTbl  = (int*)(wsb + o_stbl);
        int*             bucketTot  = (int*)(wsb + o_btot);
        int*             rowptr     = (int*)(wsb + o_rowp);
        __half*          P16        = (__half*)(wsb + o_p16);

        // ---- Layer 1: P1 = x@W1 (fp16), Q1 = x@R1 + b1 -> d_out ----
        hipMemsetAsync(bucketTot, 0, (size_t)nb * sizeof(int), stream);
        gemm_pq_kernel<<<GEMM_BLOCKS, 256, 0, stream>>>(
            x, W1, R1, b1, P16, out, N);
        p1_bin_stage<<<NBLK_G, 512, 0, stream>>>(e0, e0 + E, pairs1, blockcnt,
                                                 startsTbl, bucketTot, N, E, nb, chunk);
        p4_fine2<<<nb, 256, 0, stream>>>(pairs1, blockcnt, startsTbl, bucketTot,
                                         rowptr, csridx, N, E, nb, chunk, NBLK_G);
        // h = relu(mean-gather(P1) + Q1), in place over d_out
        fused_gather_kernel<true, false><<<GATHER_BLOCKS, 256, 0, stream>>>(
            rowptr, csridx, P16, out, N);

        // ---- Layer 2: P2 = h@W2 (fp16), Q2 = h@R2 + b2 (in-place over h) ----
        hipMemsetAsync(bucketTot, 0, (size_t)nb * sizeof(int), stream);
        gemm_pq_kernel<<<GEMM_BLOCKS, 256, 0, stream>>>(
            out, W2, R2, b2, P16, out, N);
        p1_bin_stage<<<NBLK_G, 512, 0, stream>>>(e1, e1 + E, pairs1, blockcnt,
                                                 startsTbl, bucketTot, N, E, nb, chunk);
        p4_fine2<<<nb, 256, 0, stream>>>(pairs1, blockcnt, startsTbl, bucketTot,
                                         rowptr, csridx, N, E, nb, chunk, NBLK_G);
        // out = normalize(mean-gather(P2) + Q2), in place over d_out
        fused_gather_kernel<false, true><<<GATHER_BLOCKS, 256, 0, stream>>>(
            rowptr, csridx, P16, out, N);
    } else {
        // Fallback: atomic scatter path (round-3, verified)
        float* agg = (float*)d_ws;
        float* deg = agg + (long long)N * FDIM;
        float* h = out;
        const long long total = (long long)E * FDIM;
        const int sblocks = (int)((total + 255) / 256);
        const int dblocks = (N + 3) / 4;

        hipMemsetAsync(agg, 0, ((size_t)N * FDIM + N) * sizeof(float), stream);
        scatter_kernel<<<sblocks, 256, 0, stream>>>(x, e0, e0 + E, agg, deg, N, total);
        dense_kernel<true, false><<<dblocks, 256, 0, stream>>>(agg, deg, x, W1, b1, R1, h, N);

        hipMemsetAsync(agg, 0, ((size_t)N * FDIM + N) * sizeof(float), stream);
        scatter_kernel<<<sblocks, 256, 0, stream>>>(h, e1, e1 + E, agg, deg, N, total);
        dense_kernel<false, true><<<dblocks, 256, 0, stream>>>(agg, deg, h, W2, b2, R2, out, N);
    }
}